// Round 5
// baseline (199.395 us; speedup 1.0000x reference)
//
#include <hip/hip_runtime.h>

#define NB 16   // batch
#define NN 512  // input capsules (n)
#define DI 256  // input dim (i)
#define NC 64   // output capsules (c)
#define ND 128  // capsule dim (d)
#define FO 8192 // NC*ND

// Pin a pointer into VGPRs so the compiler cannot prove it wave-uniform and
// emits a VECTOR load (L1/VMEM path, good MLP) instead of s_load (scalar
// cache: 32KB, poor MLP -> the round-4 regression).
__device__ __forceinline__ const float* pin_v(const float* p) {
  unsigned long long u = (unsigned long long)p;
  asm volatile("" : "+v"(u));
  return (const float*)u;
}

// ---------------------------------------------------------------------------
// k_tr: kT[c][d][i] = kern[i][c*128 + d]   (one-time transpose, LDS-tiled)
__global__ __launch_bounds__(256) void k_tr(const float* __restrict__ kern,
                                            float* __restrict__ kT) {
  int c = blockIdx.x;        // 0..63
  int i0 = blockIdx.y * 32;  // 8 tiles of 32 i
  int tid = threadIdx.x;
  __shared__ float buf[32][129];

#pragma unroll
  for (int k = 0; k < 4; ++k) {
    int e4 = tid + k * 256;
    int r = e4 >> 5, dq = e4 & 31;
    float4 v = *(const float4*)(kern + (size_t)(i0 + r) * FO + c * ND + dq * 4);
    buf[r][dq * 4 + 0] = v.x;
    buf[r][dq * 4 + 1] = v.y;
    buf[r][dq * 4 + 2] = v.z;
    buf[r][dq * 4 + 3] = v.w;
  }
  __syncthreads();
#pragma unroll
  for (int k = 0; k < 16; ++k) {
    int e = tid + k * 256;
    int il = e & 31, d = e >> 5;
    kT[((size_t)c * ND + d) * DI + i0 + il] = buf[il][d];
  }
}

// ---------------------------------------------------------------------------
// k_colsum: xsum_p[q][b][i] = sum over 128-n quarter of x[b][n][i]
__global__ __launch_bounds__(256) void k_colsum(const float* __restrict__ x,
                                                float* __restrict__ xsum_p) {
  int b = blockIdx.x, q = blockIdx.y;
  int tid = threadIdx.x;
  int ns = tid >> 6, i4 = tid & 63;
  float4 a = {0.f, 0.f, 0.f, 0.f};
  const float4* xp = (const float4*)(x + ((size_t)b * NN + q * 128 + ns * 32) * DI) + i4;
#pragma unroll 4
  for (int n = 0; n < 32; ++n) {
    float4 v = xp[(size_t)n * 64];
    a.x += v.x; a.y += v.y; a.z += v.z; a.w += v.w;
  }
  __shared__ float4 red[4][64];
  red[ns][i4] = a;
  __syncthreads();
  if (ns == 0) {
    float4 s0 = red[0][i4], s1 = red[1][i4], s2 = red[2][i4], s3 = red[3][i4];
    float4 s;
    s.x = s0.x + s1.x + s2.x + s3.x;
    s.y = s0.y + s1.y + s2.y + s3.y;
    s.z = s0.z + s1.z + s2.z + s3.z;
    s.w = s0.w + s1.w + s2.w + s3.w;
    ((float4*)(xsum_p + ((size_t)q * NB + b) * DI))[i4] = s;
  }
}

// ---------------------------------------------------------------------------
// k_o: per block (c, b-quad): O_raw[4,128] = Y[4,256].Kc ; O = squash -> o_ws
// K per-lane coalesced float4; y staged in LDS (small, reused).
template <bool FIRST, bool TO_OUT>
__global__ __launch_bounds__(256) void k_o(const float* __restrict__ kern,
                                           const float* __restrict__ y,
                                           const float* __restrict__ xsum_p,
                                           float* __restrict__ o_ws,
                                           float* __restrict__ outp) {
  int c = blockIdx.x, b0 = blockIdx.y * 4;
  int tid = threadIdx.x;
  __shared__ float y_lds[4][DI];
  __shared__ float4 p_lds[8][4][32];

  {
    int bb = tid >> 6, i4 = tid & 63;
    float4 v;
    if (FIRST) {
      float4 s0 = ((const float4*)(xsum_p + ((size_t)0 * NB + b0 + bb) * DI))[i4];
      float4 s1 = ((const float4*)(xsum_p + ((size_t)1 * NB + b0 + bb) * DI))[i4];
      float4 s2 = ((const float4*)(xsum_p + ((size_t)2 * NB + b0 + bb) * DI))[i4];
      float4 s3 = ((const float4*)(xsum_p + ((size_t)3 * NB + b0 + bb) * DI))[i4];
      v.x = (s0.x + s1.x + s2.x + s3.x) * (1.f / 64.f);
      v.y = (s0.y + s1.y + s2.y + s3.y) * (1.f / 64.f);
      v.z = (s0.z + s1.z + s2.z + s3.z) * (1.f / 64.f);
      v.w = (s0.w + s1.w + s2.w + s3.w) * (1.f / 64.f);
    } else {
      v = ((const float4*)(y + ((size_t)(b0 + bb) * NC + c) * DI))[i4];
    }
    ((float4*)&y_lds[bb][0])[i4] = v;
  }
  __syncthreads();

  // phase 1: thread = (i-half 0..7, d-quad 0..31)
  {
    int dq = tid & 31, half = tid >> 5;
    float4 acc[4];
#pragma unroll
    for (int bb = 0; bb < 4; ++bb) { acc[bb].x = acc[bb].y = acc[bb].z = acc[bb].w = 0.f; }
    const float* kp = kern + c * ND + dq * 4;
#pragma unroll 2
    for (int t = 0; t < 32; t += 4) {
      int i = half * 32 + t;
      float4 kv0 = *(const float4*)(kp + (size_t)(i + 0) * FO);
      float4 kv1 = *(const float4*)(kp + (size_t)(i + 1) * FO);
      float4 kv2 = *(const float4*)(kp + (size_t)(i + 2) * FO);
      float4 kv3 = *(const float4*)(kp + (size_t)(i + 3) * FO);
#pragma unroll
      for (int bb = 0; bb < 4; ++bb) {
        float4 yv = *(const float4*)&y_lds[bb][i];
        acc[bb].x += yv.x * kv0.x + yv.y * kv1.x + yv.z * kv2.x + yv.w * kv3.x;
        acc[bb].y += yv.x * kv0.y + yv.y * kv1.y + yv.z * kv2.y + yv.w * kv3.y;
        acc[bb].z += yv.x * kv0.z + yv.y * kv1.z + yv.z * kv2.z + yv.w * kv3.z;
        acc[bb].w += yv.x * kv0.w + yv.y * kv1.w + yv.z * kv2.w + yv.w * kv3.w;
      }
    }
#pragma unroll
    for (int bb = 0; bb < 4; ++bb) p_lds[half][bb][dq] = acc[bb];
  }
  __syncthreads();

  // combine + squash: wave per bb, lanes j<32 hold float4 of d
  {
    int bb = tid >> 6, j = tid & 63;
    if (j < 32) {
      float4 o; o.x = o.y = o.z = o.w = 0.f;
#pragma unroll
      for (int h = 0; h < 8; ++h) {
        float4 p = p_lds[h][bb][j];
        o.x += p.x; o.y += p.y; o.z += p.z; o.w += p.w;
      }
      float sq = o.x * o.x + o.y * o.y + o.z * o.z + o.w * o.w;
#pragma unroll
      for (int off = 16; off >= 1; off >>= 1) sq += __shfl_xor(sq, off, 64);
      float tot = sq + 1e-7f;
      float scale = sqrtf(tot) / (0.5f + tot);
      o.x *= scale; o.y *= scale; o.z *= scale; o.w *= scale;
      size_t base = ((size_t)(b0 + bb) * NC + c) * ND;
      ((float4*)(o_ws + base))[j] = o;
      if (TO_OUT) ((float4*)(outp + base))[j] = o;
    }
  }
}

// ---------------------------------------------------------------------------
// k_w: wT[b][i][c] = sum_d o[b,c,d] * kT[c][d][i].  lane = i (coalesced kT);
// o via scalar loads (2 KB, reused across all i -> sKache-resident: the GOOD
// use of scalar mem). Stride-64 scatter stores are only 16 instrs/block.
__global__ __launch_bounds__(256) void k_w(const float* __restrict__ kT,
                                           const float* __restrict__ o_ws,
                                           float* __restrict__ wT) {
  int c = blockIdx.x, b0 = blockIdx.y * 4;
  int i = threadIdx.x;
  float acc[4] = {0.f, 0.f, 0.f, 0.f};
  const float* kTc = kT + (size_t)c * ND * DI;
#pragma unroll 1
  for (int d0 = 0; d0 < ND; d0 += 4) {
    float kv0 = kTc[(size_t)(d0 + 0) * DI + i];
    float kv1 = kTc[(size_t)(d0 + 1) * DI + i];
    float kv2 = kTc[(size_t)(d0 + 2) * DI + i];
    float kv3 = kTc[(size_t)(d0 + 3) * DI + i];
#pragma unroll
    for (int bb = 0; bb < 4; ++bb) {
      float4 ov = *(const float4*)(o_ws + ((size_t)(b0 + bb) * NC + c) * ND + d0);
      acc[bb] += kv0 * ov.x + kv1 * ov.y + kv2 * ov.z + kv3 * ov.w;
    }
  }
#pragma unroll
  for (int bb = 0; bb < 4; ++bb)
    wT[((size_t)(b0 + bb) * DI + i) * NC + c] = acc[bb];
}

// ---------------------------------------------------------------------------
// k_route: b_new[b,c,n] = (ADD_B ? b_old : 0) + sum_i x[b,n,i]*wT[b,i,c]
// lane = c: wT coalesced b32; x rows as same-address VECTOR float4 broadcasts
// (wid-divergent addr + pin_v -> global_load, L1-hit). Softmax over lanes.
// No LDS, no barriers. Block (b, 32-n tile), 4 waves x 8 n.
template <bool ADD_B>
__global__ __launch_bounds__(256) void k_route(const float* __restrict__ x,
                                               const float* __restrict__ wT,
                                               float* __restrict__ blog,
                                               float* __restrict__ coef) {
  int b = blockIdx.x, n0 = blockIdx.y * 32;
  int tid = threadIdx.x;
  int lane = tid & 63, wid = tid >> 6;
  const float* wTb = wT + (size_t)b * DI * NC + lane;
  const float* xb  = x + ((size_t)b * NN + n0 + wid * 8) * DI;

  float acc[8];
#pragma unroll
  for (int k = 0; k < 8; ++k) acc[k] = 0.f;

#pragma unroll 2
  for (int ic = 0; ic < 32; ++ic) {
    int i0 = ic * 8;
    float wv[8];
#pragma unroll
    for (int j = 0; j < 8; ++j) wv[j] = wTb[(size_t)(i0 + j) * NC];
#pragma unroll
    for (int nn = 0; nn < 8; ++nn) {
      const float* xp = pin_v(xb + (size_t)nn * DI + i0);
      float4 xa = *(const float4*)xp;
      float4 xc = *(const float4*)(xp + 4);
      acc[nn] += xa.x * wv[0] + xa.y * wv[1] + xa.z * wv[2] + xa.w * wv[3] +
                 xc.x * wv[4] + xc.y * wv[5] + xc.z * wv[6] + xc.w * wv[7];
    }
  }

#pragma unroll
  for (int nn = 0; nn < 8; ++nn) {
    int n = n0 + wid * 8 + nn;
    size_t idx = ((size_t)b * NN + n) * NC + lane;
    float v = acc[nn];
    if (ADD_B) v += blog[idx];
    blog[idx] = v;
    float m = v;
#pragma unroll
    for (int off = 32; off >= 1; off >>= 1) m = fmaxf(m, __shfl_xor(m, off, 64));
    float e = __expf(v - m);
    float s = e;
#pragma unroll
    for (int off = 32; off >= 1; off >>= 1) s += __shfl_xor(s, off, 64);
    coef[idx] = e / s;
  }
}

// ---------------------------------------------------------------------------
// k_y: y[b][c][i] = sum_n coef[b][n][c] * x[b][n][i].  Block (b, c-quad).
// lane = i (coalesced x b32); coef as pinned VECTOR float4 broadcasts.
__global__ __launch_bounds__(256) void k_y(const float* __restrict__ x,
                                           const float* __restrict__ coef,
                                           float* __restrict__ y) {
  int b = blockIdx.x, c0 = blockIdx.y * 4;
  int i = threadIdx.x;
  const float* xb = x + (size_t)b * NN * DI + i;
  const float* cb = coef + (size_t)b * NN * NC + c0;
  float a0 = 0.f, a1 = 0.f, a2 = 0.f, a3 = 0.f;
#pragma unroll 4
  for (int n = 0; n < NN; ++n) {
    float xv = xb[(size_t)n * DI];
    const float* cp = pin_v(cb + (size_t)n * NC);
    float4 ca = *(const float4*)cp;
    a0 += xv * ca.x; a1 += xv * ca.y; a2 += xv * ca.z; a3 += xv * ca.w;
  }
  y[((size_t)b * NC + c0 + 0) * DI + i] = a0;
  y[((size_t)b * NC + c0 + 1) * DI + i] = a1;
  y[((size_t)b * NC + c0 + 2) * DI + i] = a2;
  y[((size_t)b * NC + c0 + 3) * DI + i] = a3;
}

// ---------------------------------------------------------------------------
extern "C" void kernel_launch(void* const* d_in, const int* in_sizes, int n_in,
                              void* d_out, int out_size, void* d_ws, size_t ws_size,
                              hipStream_t stream) {
  (void)in_sizes; (void)n_in; (void)out_size; (void)ws_size;
  const float* x    = (const float*)d_in[0];   // [16,512,256]
  const float* kern = (const float*)d_in[1];   // [256,8192]
  float* out = (float*)d_out;                  // [16,64,128]

  float* xsum_p = (float*)d_ws;                // 4*16*256    = 16384
  float* o_ws   = xsum_p + 4 * NB * DI;        // 16*64*128   = 131072
  float* wT     = o_ws + NB * NC * ND;         // 16*256*64   = 262144
  float* blog   = wT + NB * DI * NC;           // 16*512*64   = 524288
  float* coef   = blog + NB * NN * NC;         // 16*512*64   = 524288
  float* y      = coef + NB * NN * NC;         // 16*64*256   = 262144
  float* kT     = y + NB * NC * DI;            // 64*128*256  = 2097152

  k_tr<<<dim3(NC, 8), 256, 0, stream>>>(kern, kT);
  k_colsum<<<dim3(NB, 4), 256, 0, stream>>>(x, xsum_p);

  // iteration 0: uniform coefficients -> o0 -> wT0
  k_o<true, false><<<dim3(NC, 4), 256, 0, stream>>>(kern, y, xsum_p, o_ws, out);
  k_w<<<dim3(NC, 4), 256, 0, stream>>>(kT, o_ws, wT);
  k_route<false><<<dim3(NB, 16), 256, 0, stream>>>(x, wT, blog, coef);

  // iteration 1
  k_y<<<dim3(NB, 16), 256, 0, stream>>>(x, coef, y);
  k_o<false, false><<<dim3(NC, 4), 256, 0, stream>>>(kern, y, xsum_p, o_ws, out);
  k_w<<<dim3(NC, 4), 256, 0, stream>>>(kT, o_ws, wT);
  k_route<true><<<dim3(NB, 16), 256, 0, stream>>>(x, wT, blog, coef);

  // iteration 2 (final)
  k_y<<<dim3(NB, 16), 256, 0, stream>>>(x, coef, y);
  k_o<false, true><<<dim3(NC, 4), 256, 0, stream>>>(kern, y, xsum_p, o_ws, out);
}

// Round 6
// 109.924 us; speedup vs baseline: 1.8139x; 1.8139x over previous
//
#include <hip/hip_runtime.h>

#define NB 16   // batch
#define NN 512  // input capsules (n)
#define DI 256  // input dim (i)
#define NC 64   // output capsules (c)
#define ND 128  // capsule dim (d)
#define FO 8192 // NC*ND
#define NP 16   // n-tiles (split-k partials for y)

__device__ __forceinline__ int rev3(int v) {  // 3-bit bit-reverse (bijection)
  return ((v & 1) << 2) | (v & 2) | ((v >> 2) & 1);
}

// ---------------------------------------------------------------------------
// k_tr: kT[c][d][i] = kern[i][c*128 + d]   (one-time transpose, LDS-tiled)
__global__ __launch_bounds__(256) void k_tr(const float* __restrict__ kern,
                                            float* __restrict__ kT) {
  int c = blockIdx.x, i0 = blockIdx.y * 32;
  int tid = threadIdx.x;
  __shared__ float buf[32][129];
#pragma unroll
  for (int k = 0; k < 4; ++k) {
    int e4 = tid + k * 256;
    int r = e4 >> 5, dq = e4 & 31;
    float4 v = *(const float4*)(kern + (size_t)(i0 + r) * FO + c * ND + dq * 4);
    buf[r][dq * 4 + 0] = v.x; buf[r][dq * 4 + 1] = v.y;
    buf[r][dq * 4 + 2] = v.z; buf[r][dq * 4 + 3] = v.w;
  }
  __syncthreads();
#pragma unroll
  for (int k = 0; k < 16; ++k) {
    int e = tid + k * 256;
    int il = e & 31, d = e >> 5;
    kT[((size_t)c * ND + d) * DI + i0 + il] = buf[il][d];
  }
}

// ---------------------------------------------------------------------------
// k_colsum: xsum_p[q][b][i] = sum over 128-n quarter of x[b][n][i]
__global__ __launch_bounds__(256) void k_colsum(const float* __restrict__ x,
                                                float* __restrict__ xsum_p) {
  int b = blockIdx.x, q = blockIdx.y;
  int tid = threadIdx.x;
  int ns = tid >> 6, i4 = tid & 63;
  float4 a = {0.f, 0.f, 0.f, 0.f};
  const float4* xp = (const float4*)(x + ((size_t)b * NN + q * 128 + ns * 32) * DI) + i4;
#pragma unroll 4
  for (int n = 0; n < 32; ++n) {
    float4 v = xp[(size_t)n * 64];
    a.x += v.x; a.y += v.y; a.z += v.z; a.w += v.w;
  }
  __shared__ float4 red[4][64];
  red[ns][i4] = a;
  __syncthreads();
  if (ns == 0) {
    float4 s0 = red[0][i4], s1 = red[1][i4], s2 = red[2][i4], s3 = red[3][i4];
    float4 s;
    s.x = s0.x + s1.x + s2.x + s3.x;  s.y = s0.y + s1.y + s2.y + s3.y;
    s.z = s0.z + s1.z + s2.z + s3.z;  s.w = s0.w + s1.w + s2.w + s3.w;
    ((float4*)(xsum_p + ((size_t)q * NB + b) * DI))[i4] = s;
  }
}

// ---------------------------------------------------------------------------
// k_ow: per block (c, b-quad): y-combine -> O_raw = Y.Kc -> squash -> o_lds
//       (+ out store)  (+ w-phase: wT[b][i][c] = sum_d o[b,c,d]*kT[c][d][i])
template <bool FIRST, bool CALC_W, bool TO_OUT>
__global__ __launch_bounds__(256) void k_ow(const float* __restrict__ kern,
                                            const float* __restrict__ kT,
                                            const float* __restrict__ y_p,
                                            const float* __restrict__ xsum_p,
                                            float* __restrict__ wTout,
                                            float* __restrict__ outp) {
  int c = blockIdx.x, b0 = blockIdx.y * 4;
  int tid = threadIdx.x;
  __shared__ float y_lds[4][DI];      // 4 KB
  __shared__ float4 p_lds[8][4][32];  // 16 KB
  __shared__ float o_lds[4][ND];      // 2 KB

  // ---- y combine (16 split-k partials, or xsum/64 on iteration 0)
  {
    int bb = tid >> 6, i4 = tid & 63;
    float4 v;
    if (FIRST) {
      float4 s0 = ((const float4*)(xsum_p + ((size_t)0 * NB + b0 + bb) * DI))[i4];
      float4 s1 = ((const float4*)(xsum_p + ((size_t)1 * NB + b0 + bb) * DI))[i4];
      float4 s2 = ((const float4*)(xsum_p + ((size_t)2 * NB + b0 + bb) * DI))[i4];
      float4 s3 = ((const float4*)(xsum_p + ((size_t)3 * NB + b0 + bb) * DI))[i4];
      v.x = (s0.x + s1.x + s2.x + s3.x) * (1.f / 64.f);
      v.y = (s0.y + s1.y + s2.y + s3.y) * (1.f / 64.f);
      v.z = (s0.z + s1.z + s2.z + s3.z) * (1.f / 64.f);
      v.w = (s0.w + s1.w + s2.w + s3.w) * (1.f / 64.f);
    } else {
      v.x = v.y = v.z = v.w = 0.f;
#pragma unroll
      for (int p = 0; p < NP; ++p) {
        float4 t = ((const float4*)(y_p + (((size_t)p * NB + b0 + bb) * NC + c) * DI))[i4];
        v.x += t.x; v.y += t.y; v.z += t.z; v.w += t.w;
      }
    }
    ((float4*)&y_lds[bb][0])[i4] = v;
  }
  __syncthreads();

  // ---- phase 1: partial O_raw. thread = (i-half 0..7, d-quad 0..31)
  {
    int dq = tid & 31, half = tid >> 5;
    float4 acc[4];
#pragma unroll
    for (int bb = 0; bb < 4; ++bb) { acc[bb].x = acc[bb].y = acc[bb].z = acc[bb].w = 0.f; }
    const float* kp = kern + c * ND + dq * 4;
#pragma unroll 2
    for (int t = 0; t < 32; t += 4) {
      int i = half * 32 + t;
      float4 kv0 = *(const float4*)(kp + (size_t)(i + 0) * FO);
      float4 kv1 = *(const float4*)(kp + (size_t)(i + 1) * FO);
      float4 kv2 = *(const float4*)(kp + (size_t)(i + 2) * FO);
      float4 kv3 = *(const float4*)(kp + (size_t)(i + 3) * FO);
#pragma unroll
      for (int bb = 0; bb < 4; ++bb) {
        float4 yv = *(const float4*)&y_lds[bb][i];
        acc[bb].x += yv.x * kv0.x + yv.y * kv1.x + yv.z * kv2.x + yv.w * kv3.x;
        acc[bb].y += yv.x * kv0.y + yv.y * kv1.y + yv.z * kv2.y + yv.w * kv3.y;
        acc[bb].z += yv.x * kv0.z + yv.y * kv1.z + yv.z * kv2.z + yv.w * kv3.z;
        acc[bb].w += yv.x * kv0.w + yv.y * kv1.w + yv.z * kv2.w + yv.w * kv3.w;
      }
    }
#pragma unroll
    for (int bb = 0; bb < 4; ++bb) p_lds[half][bb][dq] = acc[bb];
  }
  __syncthreads();

  // ---- combine + squash (wave per bb, lanes j<32 hold d-quads)
  {
    int bb = tid >> 6, j = tid & 63;
    if (j < 32) {
      float4 o; o.x = o.y = o.z = o.w = 0.f;
#pragma unroll
      for (int h = 0; h < 8; ++h) {
        float4 p = p_lds[h][bb][j];
        o.x += p.x; o.y += p.y; o.z += p.z; o.w += p.w;
      }
      float sq = o.x * o.x + o.y * o.y + o.z * o.z + o.w * o.w;
#pragma unroll
      for (int off = 16; off >= 1; off >>= 1) sq += __shfl_xor(sq, off, 64);
      float tot = sq + 1e-7f;
      float scale = sqrtf(tot) / (0.5f + tot);
      o.x *= scale; o.y *= scale; o.z *= scale; o.w *= scale;
      ((float4*)&o_lds[bb][0])[j] = o;
      if (TO_OUT) ((float4*)outp)[((size_t)(b0 + bb) * NC + c) * 32 + j] = o;
    }
  }
  __syncthreads();

  // ---- w-phase: lane = i (coalesced kT), o broadcast from LDS
  if (CALC_W) {
    int i = tid;
    float acc[4] = {0.f, 0.f, 0.f, 0.f};
    const float* kTc = kT + (size_t)c * ND * DI;
#pragma unroll 2
    for (int d0 = 0; d0 < ND; d0 += 4) {
      float kv0 = kTc[(size_t)(d0 + 0) * DI + i];
      float kv1 = kTc[(size_t)(d0 + 1) * DI + i];
      float kv2 = kTc[(size_t)(d0 + 2) * DI + i];
      float kv3 = kTc[(size_t)(d0 + 3) * DI + i];
#pragma unroll
      for (int bb = 0; bb < 4; ++bb) {
        float4 ov = *(const float4*)&o_lds[bb][d0];
        acc[bb] += kv0 * ov.x + kv1 * ov.y + kv2 * ov.z + kv3 * ov.w;
      }
    }
#pragma unroll
    for (int bb = 0; bb < 4; ++bb)
      wTout[((size_t)(b0 + bb) * DI + i) * NC + c] = acc[bb];
  }
}

// ---------------------------------------------------------------------------
// k_ry: fused routing + partial-y per (b, 32-n tile).  256 thr = 4 waves.
//  A) logits[n][c] = x.wT  (x per-lane from swizzled LDS, w from VMEM)
//  B) blog += logits; softmax over c (lane=c, shfl)
//  C) y_p[p][b][c][i] = sum_{n in tile} coef[n][c]*x[n][i]
//     (8c x 8i register outer product; coef/x per-lane b128 from permuted LDS)
template <bool ADD_B>
__global__ __launch_bounds__(256) void k_ry(const float* __restrict__ x,
                                            const float* __restrict__ wT,
                                            float* __restrict__ blog,
                                            float* __restrict__ y_p) {
  int b = blockIdx.x, p = blockIdx.y;
  int tid = threadIdx.x;
  int lane = tid & 63, w = tid >> 6;

  __shared__ float x_n[32 * 256];  // [nl][ (iq ^ (nl&15)) quads ]  (logits)
  __shared__ float x_i[32 * 256];  // [nl][ (iq>>1) + (iq&1)*32 quads ] (y)
  __shared__ float blg[32 * 64];   // swizzled logits
  __shared__ float cf2[32 * 64];   // [n][ rev3(c>>3)*8 + (c&7) ]

  // ---- stage x tile (both layouts)
  {
    const float4* xg = (const float4*)(x + ((size_t)b * NN + p * 32) * DI);
#pragma unroll
    for (int t = 0; t < 8; ++t) {
      int e = tid + t * 256;          // 0..2047
      int nl = e >> 6, iq = e & 63;
      float4 v = xg[e];
      *(float4*)&x_n[nl * 256 + (iq ^ (nl & 15)) * 4] = v;
      *(float4*)&x_i[nl * 256 + ((iq >> 1) + (iq & 1) * 32) * 4] = v;
    }
  }
  __syncthreads();

  // ---- A: logits. lane=(nl,ch); thread owns c = ch*32+w*8 .. +7
  {
    int nl = lane & 31, ch = lane >> 5;
    int c0 = ch * 32 + w * 8;
    const float* wg = wT + (size_t)b * DI * NC + c0;
    float acc[8];
#pragma unroll
    for (int e = 0; e < 8; ++e) acc[e] = 0.f;
#pragma unroll 2
    for (int iq = 0; iq < 64; ++iq) {
      float4 xv = *(const float4*)&x_n[nl * 256 + (iq ^ (nl & 15)) * 4];
      const float* wr = wg + (size_t)iq * 4 * NC;
      float4 a0 = *(const float4*)(wr);
      float4 a1 = *(const float4*)(wr + 4);
      float4 b0 = *(const float4*)(wr + NC);
      float4 b1 = *(const float4*)(wr + NC + 4);
      float4 c0v = *(const float4*)(wr + 2 * NC);
      float4 c1v = *(const float4*)(wr + 2 * NC + 4);
      float4 d0 = *(const float4*)(wr + 3 * NC);
      float4 d1 = *(const float4*)(wr + 3 * NC + 4);
      acc[0] += xv.x * a0.x + xv.y * b0.x + xv.z * c0v.x + xv.w * d0.x;
      acc[1] += xv.x * a0.y + xv.y * b0.y + xv.z * c0v.y + xv.w * d0.y;
      acc[2] += xv.x * a0.z + xv.y * b0.z + xv.z * c0v.z + xv.w * d0.z;
      acc[3] += xv.x * a0.w + xv.y * b0.w + xv.z * c0v.w + xv.w * d0.w;
      acc[4] += xv.x * a1.x + xv.y * b1.x + xv.z * c1v.x + xv.w * d1.x;
      acc[5] += xv.x * a1.y + xv.y * b1.y + xv.z * c1v.y + xv.w * d1.y;
      acc[6] += xv.x * a1.z + xv.y * b1.z + xv.z * c1v.z + xv.w * d1.z;
      acc[7] += xv.x * a1.w + xv.y * b1.w + xv.z * c1v.w + xv.w * d1.w;
    }
    // write logits to swizzled LDS
#pragma unroll
    for (int e = 0; e < 8; ++e)
      blg[nl * 64 + ((c0 + e) ^ ((nl & 15) << 2))] = acc[e];
  }
  __syncthreads();

  // ---- B: blog add + softmax over c. lane = c; wave w owns n = w*8..+7
  {
#pragma unroll
    for (int nn = 0; nn < 8; ++nn) {
      int n = w * 8 + nn;
      float v = blg[n * 64 + (lane ^ ((n & 15) << 2))];
      size_t gi = ((size_t)b * NN + p * 32 + n) * NC + lane;
      if (ADD_B) v += blog[gi];
      blog[gi] = v;
      float m = v;
#pragma unroll
      for (int off = 32; off >= 1; off >>= 1) m = fmaxf(m, __shfl_xor(m, off, 64));
      float e = __expf(v - m);
      float s = e;
#pragma unroll
      for (int off = 32; off >= 1; off >>= 1) s += __shfl_xor(s, off, 64);
      cf2[n * 64 + rev3(lane >> 3) * 8 + (lane & 7)] = e / s;
    }
  }
  __syncthreads();

  // ---- C: partial y. lane = (m,k): c = m*8+cc, i = w*64 + k*8 + ii
  {
    int m8 = lane >> 3, k = lane & 7;
    float acc[64];
#pragma unroll
    for (int e = 0; e < 64; ++e) acc[e] = 0.f;
#pragma unroll 2
    for (int n = 0; n < 32; ++n) {
      float4 cfa = *(const float4*)&cf2[n * 64 + rev3(m8) * 8];
      float4 cfb = *(const float4*)&cf2[n * 64 + rev3(m8) * 8 + 4];
      float4 xa = *(const float4*)&x_i[n * 256 + (w * 8 + k) * 4];
      float4 xb = *(const float4*)&x_i[n * 256 + (w * 8 + k + 32) * 4];
      float cf[8] = {cfa.x, cfa.y, cfa.z, cfa.w, cfb.x, cfb.y, cfb.z, cfb.w};
      float xv[8] = {xa.x, xa.y, xa.z, xa.w, xb.x, xb.y, xb.z, xb.w};
#pragma unroll
      for (int cc = 0; cc < 8; ++cc)
#pragma unroll
        for (int ii = 0; ii < 8; ++ii)
          acc[cc * 8 + ii] += cf[cc] * xv[ii];
    }
    float* yp = y_p + ((size_t)p * NB + b) * NC * DI;
#pragma unroll
    for (int cc = 0; cc < 8; ++cc) {
      float4 v0 = {acc[cc * 8 + 0], acc[cc * 8 + 1], acc[cc * 8 + 2], acc[cc * 8 + 3]};
      float4 v1 = {acc[cc * 8 + 4], acc[cc * 8 + 5], acc[cc * 8 + 6], acc[cc * 8 + 7]};
      size_t base = (size_t)(m8 * 8 + cc) * DI + w * 64 + k * 8;
      *(float4*)(yp + base) = v0;
      *(float4*)(yp + base + 4) = v1;
    }
  }
}

// ---------------------------------------------------------------------------
extern "C" void kernel_launch(void* const* d_in, const int* in_sizes, int n_in,
                              void* d_out, int out_size, void* d_ws, size_t ws_size,
                              hipStream_t stream) {
  (void)in_sizes; (void)n_in; (void)out_size; (void)ws_size;
  const float* x    = (const float*)d_in[0];   // [16,512,256]
  const float* kern = (const float*)d_in[1];   // [256,8192]
  float* out = (float*)d_out;                  // [16,64,128]

  float* xsum_p = (float*)d_ws;                  // 4*16*256       = 16384
  float* wT     = xsum_p + 4 * NB * DI;          // 16*256*64      = 262144
  float* blog   = wT + NB * DI * NC;             // 16*512*64      = 524288
  float* y_p    = blog + NB * NN * NC;           // 16*16*64*256   = 4194304
  float* kT     = y_p + (size_t)NP * NB * NC * DI; // 64*128*256   = 2097152

  k_tr<<<dim3(NC, 8), 256, 0, stream>>>(kern, kT);
  k_colsum<<<dim3(NB, 4), 256, 0, stream>>>(x, xsum_p);

  // iteration 0: uniform coefficients -> o0 -> wT0
  k_ow<true, true, false><<<dim3(NC, 4), 256, 0, stream>>>(kern, kT, y_p, xsum_p, wT, out);
  k_ry<false><<<dim3(NB, NP), 256, 0, stream>>>(x, wT, blog, y_p);

  // iteration 1
  k_ow<false, true, false><<<dim3(NC, 4), 256, 0, stream>>>(kern, kT, y_p, xsum_p, wT, out);
  k_ry<true><<<dim3(NB, NP), 256, 0, stream>>>(x, wT, blog, y_p);

  // iteration 2 (final)
  k_ow<false, false, true><<<dim3(NC, 4), 256, 0, stream>>>(kern, kT, y_p, xsum_p, wT, out);
}

// Round 7
// 74.653 us; speedup vs baseline: 2.6709x; 1.4725x over previous
//
#include <hip/hip_runtime.h>
#include <hip/hip_bf16.h>

#define NB 16   // batch
#define NN 512  // input capsules (n)
#define DI 256  // input dim (i)
#define NC 64   // output capsules (c)
#define ND 128  // capsule dim (d)
#define FO 8192 // NC*ND
#define NP 16   // n-tiles (split-k partials for y)

typedef __attribute__((ext_vector_type(8))) short short8v;
typedef __attribute__((ext_vector_type(4))) short short4v;
typedef __attribute__((ext_vector_type(4))) float f32x4;

__device__ __forceinline__ unsigned short f2b(float f) {
  union { __hip_bfloat16 h; unsigned short u; } cv;
  cv.h = __float2bfloat16(f);
  return cv.u;
}

// ---------------------------------------------------------------------------
// k_pre: task-split prep kernel.
//  tasks [0,512):    kT[c][d][i] = kern[i][c*128+d]      (for k_ow w-phase)
//  tasks [512,1024): xh[b][n][i], xhT[b][i][n]  bf16 casts of x
//  tasks [1024,1088): xsum_p[q][b][i] = colsum of x over 128-n quarter
__global__ __launch_bounds__(256) void k_pre(const float* __restrict__ x,
                                             const float* __restrict__ kern,
                                             float* __restrict__ kT,
                                             unsigned short* __restrict__ xh,
                                             unsigned short* __restrict__ xhT,
                                             float* __restrict__ xsum_p) {
  int task = blockIdx.x;
  int tid = threadIdx.x;

  if (task < 512) {  // ---- kT transpose (round-6 k_tr verbatim)
    int c = task >> 3, i0 = (task & 7) * 32;
    __shared__ float buf[32][129];
#pragma unroll
    for (int k = 0; k < 4; ++k) {
      int e4 = tid + k * 256;
      int r = e4 >> 5, dq = e4 & 31;
      float4 v = *(const float4*)(kern + (size_t)(i0 + r) * FO + c * ND + dq * 4);
      buf[r][dq * 4 + 0] = v.x; buf[r][dq * 4 + 1] = v.y;
      buf[r][dq * 4 + 2] = v.z; buf[r][dq * 4 + 3] = v.w;
    }
    __syncthreads();
#pragma unroll
    for (int k = 0; k < 16; ++k) {
      int e = tid + k * 256;
      int il = e & 31, d = e >> 5;
      kT[((size_t)c * ND + d) * DI + i0 + il] = buf[il][d];
    }
  } else if (task < 1024) {  // ---- bf16 cast + transpose of x (64n x 64i tile)
    int idx = task - 512;
    int b = idx >> 5, rem = idx & 31;
    int nb = (rem >> 2) * 64, ib = (rem & 3) * 64;
    __shared__ float buf2[64][68];
    // stage 64x64 f32
#pragma unroll
    for (int k = 0; k < 4; ++k) {
      int e4 = tid + k * 256;              // 0..1023
      int nl = e4 >> 4, q4 = e4 & 15;
      float4 v = *(const float4*)(x + ((size_t)b * NN + nb + nl) * DI + ib + q4 * 4);
      *(float4*)&buf2[nl][q4 * 4] = v;
    }
    __syncthreads();
    // xh[b][n][i] bf16 (row-major, coalesced)
    {
      int nl = tid >> 2, ig = (tid & 3) * 16;
      unsigned short tmp[16];
#pragma unroll
      for (int e = 0; e < 16; ++e) tmp[e] = f2b(buf2[nl][ig + e]);
      unsigned short* dst = xh + ((size_t)b * NN + nb + nl) * DI + ib + ig;
      *(short8v*)dst = *(short8v*)tmp;
      *(short8v*)(dst + 8) = *(short8v*)(tmp + 8);
    }
    // xhT[b][i][n] bf16 (transposed)
    {
      int il = tid & 63, ng = tid >> 6;    // wave-uniform ng
      unsigned short tmp[16];
#pragma unroll
      for (int e = 0; e < 16; ++e) tmp[e] = f2b(buf2[ng * 16 + e][il]);
      unsigned short* dst = xhT + ((size_t)b * DI + ib + il) * NN + nb + ng * 16;
      *(short8v*)dst = *(short8v*)tmp;
      *(short8v*)(dst + 8) = *(short8v*)(tmp + 8);
    }
  } else {  // ---- column sums (round-6 k_colsum)
    int idx = task - 1024;
    int b = idx >> 2, q = idx & 3;
    int ns = tid >> 6, i4 = tid & 63;
    float4 a = {0.f, 0.f, 0.f, 0.f};
    const float4* xp = (const float4*)(x + ((size_t)b * NN + q * 128 + ns * 32) * DI) + i4;
#pragma unroll 4
    for (int n = 0; n < 32; ++n) {
      float4 v = xp[(size_t)n * 64];
      a.x += v.x; a.y += v.y; a.z += v.z; a.w += v.w;
    }
    __shared__ float4 red[4][64];
    red[ns][i4] = a;
    __syncthreads();
    if (ns == 0) {
      float4 s0 = red[0][i4], s1 = red[1][i4], s2 = red[2][i4], s3 = red[3][i4];
      float4 s;
      s.x = s0.x + s1.x + s2.x + s3.x;  s.y = s0.y + s1.y + s2.y + s3.y;
      s.z = s0.z + s1.z + s2.z + s3.z;  s.w = s0.w + s1.w + s2.w + s3.w;
      ((float4*)(xsum_p + ((size_t)q * NB + b) * DI))[i4] = s;
    }
  }
}

// ---------------------------------------------------------------------------
// k_ow (round-6 proven version; only w-output changed to bf16 whc[b][c][i]):
// per block (c, b-quad): y-combine -> O_raw = Y.Kc -> squash -> o_lds
//  (+ out store)  (+ w-phase: w[b,c,i] = sum_d o[b,c,d]*kT[c][d][i] -> bf16)
template <bool FIRST, bool CALC_W, bool TO_OUT>
__global__ __launch_bounds__(256) void k_ow(const float* __restrict__ kern,
                                            const float* __restrict__ kT,
                                            const float* __restrict__ y_p,
                                            const float* __restrict__ xsum_p,
                                            unsigned short* __restrict__ whc,
                                            float* __restrict__ outp) {
  int c = blockIdx.x, b0 = blockIdx.y * 4;
  int tid = threadIdx.x;
  __shared__ float y_lds[4][DI];      // 4 KB
  __shared__ float4 p_lds[8][4][32];  // 16 KB
  __shared__ float o_lds[4][ND];      // 2 KB

  // ---- y combine (16 split-k partials, or xsum/64 on iteration 0)
  {
    int bb = tid >> 6, i4 = tid & 63;
    float4 v;
    if (FIRST) {
      float4 s0 = ((const float4*)(xsum_p + ((size_t)0 * NB + b0 + bb) * DI))[i4];
      float4 s1 = ((const float4*)(xsum_p + ((size_t)1 * NB + b0 + bb) * DI))[i4];
      float4 s2 = ((const float4*)(xsum_p + ((size_t)2 * NB + b0 + bb) * DI))[i4];
      float4 s3 = ((const float4*)(xsum_p + ((size_t)3 * NB + b0 + bb) * DI))[i4];
      v.x = (s0.x + s1.x + s2.x + s3.x) * (1.f / 64.f);
      v.y = (s0.y + s1.y + s2.y + s3.y) * (1.f / 64.f);
      v.z = (s0.z + s1.z + s2.z + s3.z) * (1.f / 64.f);
      v.w = (s0.w + s1.w + s2.w + s3.w) * (1.f / 64.f);
    } else {
      v.x = v.y = v.z = v.w = 0.f;
#pragma unroll
      for (int p = 0; p < NP; ++p) {
        float4 t = ((const float4*)(y_p + (((size_t)p * NB + b0 + bb) * NC + c) * DI))[i4];
        v.x += t.x; v.y += t.y; v.z += t.z; v.w += t.w;
      }
    }
    ((float4*)&y_lds[bb][0])[i4] = v;
  }
  __syncthreads();

  // ---- phase 1: partial O_raw. thread = (i-half 0..7, d-quad 0..31)
  {
    int dq = tid & 31, half = tid >> 5;
    f32x4 acc[4];
#pragma unroll
    for (int bb = 0; bb < 4; ++bb) { acc[bb][0] = acc[bb][1] = acc[bb][2] = acc[bb][3] = 0.f; }
    const float* kp = kern + c * ND + dq * 4;
#pragma unroll 2
    for (int t = 0; t < 32; t += 4) {
      int i = half * 32 + t;
      float4 kv0 = *(const float4*)(kp + (size_t)(i + 0) * FO);
      float4 kv1 = *(const float4*)(kp + (size_t)(i + 1) * FO);
      float4 kv2 = *(const float4*)(kp + (size_t)(i + 2) * FO);
      float4 kv3 = *(const float4*)(kp + (size_t)(i + 3) * FO);
#pragma unroll
      for (int bb = 0; bb < 4; ++bb) {
        float4 yv = *(const float4*)&y_lds[bb][i];
        acc[bb][0] += yv.x * kv0.x + yv.y * kv1.x + yv.z * kv2.x + yv.w * kv3.x;
        acc[bb][1] += yv.x * kv0.y + yv.y * kv1.y + yv.z * kv2.y + yv.w * kv3.y;
        acc[bb][2] += yv.x * kv0.z + yv.y * kv1.z + yv.z * kv2.z + yv.w * kv3.z;
        acc[bb][3] += yv.x * kv0.w + yv.y * kv1.w + yv.z * kv2.w + yv.w * kv3.w;
      }
    }
#pragma unroll
    for (int bb = 0; bb < 4; ++bb) {
      float4 st = {acc[bb][0], acc[bb][1], acc[bb][2], acc[bb][3]};
      p_lds[half][bb][dq] = st;
    }
  }
  __syncthreads();

  // ---- combine + squash (wave per bb, lanes j<32 hold d-quads)
  {
    int bb = tid >> 6, j = tid & 63;
    if (j < 32) {
      float4 o; o.x = o.y = o.z = o.w = 0.f;
#pragma unroll
      for (int h = 0; h < 8; ++h) {
        float4 p = p_lds[h][bb][j];
        o.x += p.x; o.y += p.y; o.z += p.z; o.w += p.w;
      }
      float sq = o.x * o.x + o.y * o.y + o.z * o.z + o.w * o.w;
#pragma unroll
      for (int off = 16; off >= 1; off >>= 1) sq += __shfl_xor(sq, off, 64);
      float tot = sq + 1e-7f;
      float scale = sqrtf(tot) / (0.5f + tot);
      o.x *= scale; o.y *= scale; o.z *= scale; o.w *= scale;
      ((float4*)&o_lds[bb][0])[j] = o;
      if (TO_OUT) ((float4*)outp)[((size_t)(b0 + bb) * NC + c) * 32 + j] = o;
    }
  }
  __syncthreads();

  // ---- w-phase: lane = i (coalesced kT), o broadcast from LDS -> bf16 out
  if (CALC_W) {
    int i = tid;
    float acc[4] = {0.f, 0.f, 0.f, 0.f};
    const float* kTc = kT + (size_t)c * ND * DI;
#pragma unroll 2
    for (int d0 = 0; d0 < ND; d0 += 4) {
      float kv0 = kTc[(size_t)(d0 + 0) * DI + i];
      float kv1 = kTc[(size_t)(d0 + 1) * DI + i];
      float kv2 = kTc[(size_t)(d0 + 2) * DI + i];
      float kv3 = kTc[(size_t)(d0 + 3) * DI + i];
#pragma unroll
      for (int bb = 0; bb < 4; ++bb) {
        float4 ov = *(const float4*)&o_lds[bb][d0];
        acc[bb] += kv0 * ov.x + kv1 * ov.y + kv2 * ov.z + kv3 * ov.w;
      }
    }
#pragma unroll
    for (int bb = 0; bb < 4; ++bb)
      whc[((size_t)(b0 + bb) * NC + c) * DI + i] = f2b(acc[bb]);
  }
}

// ---------------------------------------------------------------------------
// k_sy: MFMA bf16 fused (logits -> softmax -> partial-y) per (b, 32-n tile).
// 512 threads = 8 waves.
//  logits sT[c][n] = sum_i w[c][i]*x[n][i]:  A = whc[c][i], B = xh[n][i]
//  softmax over c (lane=c), blog add/store, coef -> bf16 LDS cT[c][n]
//  y_p[p][b][c][i] = sum_n coef[c][n]*x[n][i]: A = cT, B = xhT[i][n]
template <bool ADD_B, bool STORE_B>
__global__ __launch_bounds__(512) void k_sy(const unsigned short* __restrict__ xh,
                                            const unsigned short* __restrict__ xhT,
                                            const unsigned short* __restrict__ whc,
                                            float* __restrict__ blog,
                                            float* __restrict__ y_p) {
  int b = blockIdx.x, p = blockIdx.y;
  int tid = threadIdx.x;
  int lane = tid & 63, w = tid >> 6;     // 8 waves
  int m16 = lane & 15, ko = lane >> 4;   // fragment coords

  __shared__ float s_lds[32][65];        // logits [n_local][c]
  __shared__ unsigned short cT[64][40];  // coef bf16 [c][n_local] (pad 40)

  int n0 = p * 32;

  // ---- logits: wave w -> Mt = w&3 (c-tile), Nt = w>>2 (n-tile)
  {
    int Mt = w & 3, Nt = w >> 2;
    const unsigned short* wrow = whc + ((size_t)b * NC + Mt * 16 + m16) * DI + ko * 8;
    const unsigned short* xrow = xh + ((size_t)b * NN + n0 + Nt * 16 + m16) * DI + ko * 8;
    f32x4 acc = {0.f, 0.f, 0.f, 0.f};
#pragma unroll
    for (int k8 = 0; k8 < 8; ++k8) {
      short8v av = *(const short8v*)(wrow + k8 * 32);
      short8v bv = *(const short8v*)(xrow + k8 * 32);
      acc = __builtin_amdgcn_mfma_f32_16x16x32_bf16(av, bv, acc, 0, 0, 0);
    }
    // D: col = lane&15 -> n_local; row = ko*4+r -> c_local  [HW-verified m89]
#pragma unroll
    for (int r = 0; r < 4; ++r)
      s_lds[Nt * 16 + m16][Mt * 16 + ko * 4 + r] = acc[r];
  }
  __syncthreads();

  // ---- softmax over c (lane = c); wave w owns n = w*4 .. +3
  {
    unsigned short pk[4];
#pragma unroll
    for (int nn = 0; nn < 4; ++nn) {
      int n = w * 4 + nn;
      float v = s_lds[n][lane];
      size_t gi = ((size_t)b * NN + n0 + n) * NC + lane;
      if (ADD_B) v += blog[gi];
      if (STORE_B) blog[gi] = v;
      float m = v;
#pragma unroll
      for (int off = 32; off >= 1; off >>= 1) m = fmaxf(m, __shfl_xor(m, off, 64));
      float e = __expf(v - m);
      float s = e;
#pragma unroll
      for (int off = 32; off >= 1; off >>= 1) s += __shfl_xor(s, off, 64);
      pk[nn] = f2b(e / s);
    }
    *(short4v*)&cT[lane][w * 4] = *(short4v*)pk;
  }
  __syncthreads();

  // ---- y partial: wave w -> Mt in {2*(w>>2), +1}, Nt = (w&3)*4 + q
  {
    int Mp = w >> 2, Ng = w & 3;
    short8v a0 = *(const short8v*)&cT[(Mp * 2 + 0) * 16 + m16][ko * 8];
    short8v a1 = *(const short8v*)&cT[(Mp * 2 + 1) * 16 + m16][ko * 8];
    f32x4 acc[2][4];
#pragma unroll
    for (int t = 0; t < 2; ++t)
#pragma unroll
      for (int q = 0; q < 4; ++q) { acc[t][q][0]=acc[t][q][1]=acc[t][q][2]=acc[t][q][3]=0.f; }
#pragma unroll
    for (int q = 0; q < 4; ++q) {
      int icol = (Ng * 4 + q) * 16 + m16;
      short8v bv = *(const short8v*)(xhT + ((size_t)b * DI + icol) * NN + n0 + ko * 8);
      acc[0][q] = __builtin_amdgcn_mfma_f32_16x16x32_bf16(a0, bv, acc[0][q], 0, 0, 0);
      acc[1][q] = __builtin_amdgcn_mfma_f32_16x16x32_bf16(a1, bv, acc[1][q], 0, 0, 0);
    }
    float* yb = y_p + ((size_t)p * NB + b) * NC * DI;
#pragma unroll
    for (int t = 0; t < 2; ++t)
#pragma unroll
      for (int q = 0; q < 4; ++q)
#pragma unroll
        for (int r = 0; r < 4; ++r)
          yb[(size_t)((Mp * 2 + t) * 16 + ko * 4 + r) * DI + (Ng * 4 + q) * 16 + m16] =
              acc[t][q][r];
  }
}

// ---------------------------------------------------------------------------
extern "C" void kernel_launch(void* const* d_in, const int* in_sizes, int n_in,
                              void* d_out, int out_size, void* d_ws, size_t ws_size,
                              hipStream_t stream) {
  (void)in_sizes; (void)n_in; (void)out_size; (void)ws_size;
  const float* x    = (const float*)d_in[0];   // [16,512,256]
  const float* kern = (const float*)d_in[1];   // [256,8192]
  float* out = (float*)d_out;                  // [16,64,128]

  float* xsum_p = (float*)d_ws;                     // 4*16*256        = 16384 f
  float* y_p    = xsum_p + 4 * NB * DI;             // 16*16*64*256    = 4194304 f
  float* blog   = y_p + (size_t)NP * NB * NC * DI;  // 16*512*64       = 524288 f
  float* kT     = blog + (size_t)NB * NN * NC;      // 64*128*256      = 2097152 f
  unsigned short* xh  = (unsigned short*)(kT + (size_t)NC * ND * DI);  // 2097152 us
  unsigned short* xhT = xh + (size_t)NB * NN * DI;                     // 2097152 us
  unsigned short* whc = xhT + (size_t)NB * DI * NN;                    // 262144 us

  k_pre<<<1088, 256, 0, stream>>>(x, kern, kT, xh, xhT, xsum_p);

  // iteration 0: uniform coefficients -> o0 -> w0 (bf16)
  k_ow<true, true, false><<<dim3(NC, 4), 256, 0, stream>>>(kern, kT, y_p, xsum_p, whc, out);
  // iteration 1: logits1 (store blog), softmax, y-partials
  k_sy<false, true><<<dim3(NB, NP), 512, 0, stream>>>(xh, xhT, whc, blog, y_p);
  k_ow<false, true, false><<<dim3(NC, 4), 256, 0, stream>>>(kern, kT, y_p, xsum_p, whc, out);
  // iteration 2: logits2 (+blog), softmax, y-partials
  k_sy<true, false><<<dim3(NB, NP), 512, 0, stream>>>(xh, xhT, whc, blog, y_p);
  k_ow<false, false, true><<<dim3(NC, 4), 256, 0, stream>>>(kern, kT, y_p, xsum_p, whc, out);
}